// Round 7
// baseline (237.706 us; speedup 1.0000x reference)
//
#include <hip/hip_runtime.h>

// LNCC, separable 5-tap Gaussian (sigma=1), fused single pass.
// (N=2, C=1, D=160, H=192, W=224) fp32 -> scalar.
// R12: LDS-issue-bound per R8/R11 arithmetic (LDS pipe ~80%, VALU 50%, HBM 23%).
//      Tile 32x16 -> 32x32 (2 output rows/thread), DCHUNK 20->10 so grid stays
//      (7,6,32)=1344 blocks (same as proven R8; R10 showed small grids starve).
//      H-blur reads 6 taps per 2 outputs (was 5 per 1) -> dominant DS item
//      -40%; barrier-iters -38%. Block stays 640 thr (R7's 320-thr version of
//      this idea lost on occupancy). LDS 67KB/block (gfx950 WG max 160KB;
//      2 blocks/CU fit). Keeps packed-fp32 v2f math + lgkm-only barrier.

#define NB 2
#define DD 160
#define HH 192
#define WW 224
#define SH 224
#define SD (224*192)
#define SN (224*192*160)

#define TW 32
#define TH 32
#define ROWS (TH+4)          // 36 staged rows
#define DCHUNK 10
#define NCHUNK (DD/DCHUNK)   // 16

#define K0 0.05448868f
#define K1 0.24420134f
#define K2 0.40261995f

typedef float v2f __attribute__((ext_vector_type(2)));
typedef float v4f __attribute__((ext_vector_type(4)));

__global__ __launch_bounds__(640) void lncc_main(
    const float* __restrict__ A, const float* __restrict__ B,
    const float* __restrict__ M, double* __restrict__ acc)
{
    __shared__ v2f  sIJ[2][ROWS][36];   // raw (I,J) + W halo, dbuf  (20.7 KB)
    __shared__ v4f  wbA[2][ROWS][32];   // (bI,bJ,bII,bJJ), dbuf     (36.9 KB)
    __shared__ float wbC[2][ROWS][32];  // bIJ, dbuf                 ( 9.2 KB)
    __shared__ float redL[10], redM[10];

    const int wt = blockIdx.x;           // 0..6
    const int ht = blockIdx.y;           // 0..5
    const int zz = blockIdx.z;           // 0..31
    const int n  = zz >> 4;
    const int dc = zz & 15;
    const int w0 = wt * TW, h0 = ht * TH, d0 = dc * DCHUNK;

    const float* __restrict__ Ai = A + (size_t)n * SN;
    const float* __restrict__ Bi = B + (size_t)n * SN;
    const float* __restrict__ Mi = M + (size_t)n * SN;

    const int tid = threadIdx.x;
    const int rr  = tid >> 5;            // 0..19 (row-pair index)
    const int c   = tid & 31;            // 0..31
    const int sa  = rr * 2;              // staged rows owned: sa, sa+1
    const int sb  = sa + 1;
    const bool stv = (rr < 18);          // stage+W-blur rows 0..35
    const bool orv = (rr < 16);          // output rows 0..31

    // ---- per-row global addressing ----
    const int gha = h0 + sa - 2;
    const int ghb = gha + 1;
    const bool hva = stv && ((unsigned)gha < (unsigned)HH);
    const bool hvb = stv && ((unsigned)ghb < (unsigned)HH);
    const int ghca = hva ? gha : 0;
    const int ghcb = hvb ? ghb : 0;
    const int hwma = ghca * SH + (w0 + c);
    const int hwmb = ghcb * SH + (w0 + c);

    const int gwl = w0 + c - 2, gwr = w0 + c + 2;
    const bool lc = (c < 2)   && (gwl >= 0);
    const bool rc = (c >= 30) && (gwr < WW);
    const int  whx = lc ? gwl : (rc ? gwr : 0);
    const bool anyc  = lc || rc;
    const bool anyha = anyc && hva;
    const bool anyhb = anyc && hvb;
    const int hwha = ghca * SH + whx;
    const int hwhb = ghcb * SH + whx;

    const int mbasea = (h0 + sa) * SH + (w0 + c);   // output row a (= h0+2rr)
    const int mbaseb = mbasea + SH;                 // output row b

    // D-direction shift-register pipelines, rows a and b (oldest..newest)
    v2f pP0a=0.f,pP1a=0.f,pP2a=0.f,pP3a=0.f;   // (bI,bJ)   row a
    v2f pQ0a=0.f,pQ1a=0.f,pQ2a=0.f,pQ3a=0.f;   // (bII,bJJ) row a
    float pC0a=0.f,pC1a=0.f,pC2a=0.f,pC3a=0.f; // bIJ       row a
    v2f pP0b=0.f,pP1b=0.f,pP2b=0.f,pP3b=0.f;
    v2f pQ0b=0.f,pQ1b=0.f,pQ2b=0.f,pQ3b=0.f;
    float pC0b=0.f,pC1b=0.f,pC2b=0.f,pC3b=0.f;
    float accL = 0.f, accM = 0.f;

    // prefetch registers for the slice staged at iteration k
    v2f nMa = 0.f, nMb = 0.f, nHa = 0.f, nHb = 0.f;
    {
        const int dd = d0 - 2;
        if (dd >= 0) {
            const int dof = dd * SD;
            if (hva)  { nMa.x = Ai[dof + hwma]; nMa.y = Bi[dof + hwma]; }
            if (hvb)  { nMb.x = Ai[dof + hwmb]; nMb.y = Bi[dof + hwmb]; }
            if (anyha){ nHa.x = Ai[dof + hwha]; nHa.y = Bi[dof + hwha]; }
            if (anyhb){ nHb.x = Ai[dof + hwhb]; nHb.y = Bi[dof + hwhb]; }
        }
    }

    const int NIT = DCHUNK + 6;          // 16
#pragma unroll 2
    for (int k = 0; k < NIT; ++k) {
        const int pw = k & 1;            // parity staged THIS iter
        const int px = pw ^ 1;

        // ---- W: stage prefetched raw slice (slices d0-2 .. d0+DCHUNK+1) ----
        if (k < DCHUNK + 4 && stv) {
            sIJ[pw][sa][c + 2] = nMa;
            sIJ[pw][sb][c + 2] = nMb;
            if (c < 2) {
                sIJ[pw][sa][c] = nHa;
                sIJ[pw][sb][c] = nHb;
            } else if (c >= 30) {
                sIJ[pw][sa][c + 4] = nHa;
                sIJ[pw][sb][c + 4] = nHb;
            }
        }

        // ---- prefetch slice k+1 ----
        nMa = 0.f; nMb = 0.f; nHa = 0.f; nHb = 0.f;
        {
            const int dd = d0 - 1 + k;
            if ((k + 1 < DCHUNK + 4) && (dd >= 0) && (dd < DD)) {
                const int dof = dd * SD;
                if (hva)  { nMa.x = Ai[dof + hwma]; nMa.y = Bi[dof + hwma]; }
                if (hvb)  { nMb.x = Ai[dof + hwmb]; nMb.y = Bi[dof + hwmb]; }
                if (anyha){ nHa.x = Ai[dof + hwha]; nHa.y = Bi[dof + hwha]; }
                if (anyhb){ nHb.x = Ai[dof + hwhb]; nHb.y = Bi[dof + hwhb]; }
            }
        }

        // ---- this iteration's mask values ----
        const int  dout = d0 - 6 + k;
        const bool outv = (k >= 6) && orv;
        float mvala = 0.f, mvalb = 0.f;
        if (outv) {
            mvala = Mi[dout * SD + mbasea];
            mvalb = Mi[dout * SD + mbaseb];
        }

        // ---- X: W-blur of slice staged last iteration (rows sa, sb) ----
        if (k >= 1 && k <= DCHUNK + 4 && stv) {
            {
                const v2f v0 = sIJ[px][sa][c];
                const v2f v1 = sIJ[px][sa][c + 1];
                const v2f v2 = sIJ[px][sa][c + 2];
                const v2f v3 = sIJ[px][sa][c + 3];
                const v2f v4 = sIJ[px][sa][c + 4];
                const v2f b  = K0*(v0+v4) + K1*(v1+v3) + K2*v2;
                const v2f bs = K0*(v0*v0+v4*v4) + K1*(v1*v1+v3*v3) + K2*(v2*v2);
                const float bij = K0*(v0.x*v0.y+v4.x*v4.y) + K1*(v1.x*v1.y+v3.x*v3.y) + K2*(v2.x*v2.y);
                wbA[px][sa][c] = (v4f){b.x, b.y, bs.x, bs.y};
                wbC[px][sa][c] = bij;
            }
            {
                const v2f v0 = sIJ[px][sb][c];
                const v2f v1 = sIJ[px][sb][c + 1];
                const v2f v2 = sIJ[px][sb][c + 2];
                const v2f v3 = sIJ[px][sb][c + 3];
                const v2f v4 = sIJ[px][sb][c + 4];
                const v2f b  = K0*(v0+v4) + K1*(v1+v3) + K2*v2;
                const v2f bs = K0*(v0*v0+v4*v4) + K1*(v1*v1+v3*v3) + K2*(v2*v2);
                const float bij = K0*(v0.x*v0.y+v4.x*v4.y) + K1*(v1.x*v1.y+v3.x*v3.y) + K2*(v2.x*v2.y);
                wbA[px][sb][c] = (v4f){b.x, b.y, bs.x, bs.y};
                wbC[px][sb][c] = bij;
            }
        }

        // ---- Y: H-blur (6 taps -> 2 output rows) + D-pipelines ----
        if (k >= 2 && orv) {
            const v4f a0 = wbA[pw][sa    ][c];
            const v4f a1 = wbA[pw][sa + 1][c];
            const v4f a2 = wbA[pw][sa + 2][c];
            const v4f a3 = wbA[pw][sa + 3][c];
            const v4f a4 = wbA[pw][sa + 4][c];
            const v4f a5 = wbA[pw][sa + 5][c];
            const float e0 = wbC[pw][sa    ][c];
            const float e1 = wbC[pw][sa + 1][c];
            const float e2 = wbC[pw][sa + 2][c];
            const float e3 = wbC[pw][sa + 3][c];
            const float e4 = wbC[pw][sa + 4][c];
            const float e5 = wbC[pw][sa + 5][c];

            const v2f h1a = K0*(a0.xy+a4.xy) + K1*(a1.xy+a3.xy) + K2*a2.xy;
            const v2f h2a = K0*(a0.zw+a4.zw) + K1*(a1.zw+a3.zw) + K2*a2.zw;
            const float hca = K0*(e0+e4) + K1*(e1+e3) + K2*e2;

            const v2f h1b = K0*(a1.xy+a5.xy) + K1*(a2.xy+a4.xy) + K2*a3.xy;
            const v2f h2b = K0*(a1.zw+a5.zw) + K1*(a2.zw+a4.zw) + K2*a3.zw;
            const float hcb = K0*(e1+e5) + K1*(e2+e4) + K2*e3;

            if (outv) {
                {
                    const v2f bP = K0*(pP0a+h1a) + K1*(pP1a+pP3a) + K2*pP2a;
                    const v2f bS = K0*(pQ0a+h2a) + K1*(pQ1a+pQ3a) + K2*pQ2a;
                    const float bC = K0*(pC0a+hca) + K1*(pC1a+pC3a) + K2*pC2a;
                    const float cross = bC - bP.x * bP.y;
                    const float vI = fmaxf(bS.x - bP.x * bP.x, 0.f) + 1e-5f;
                    const float vJ = fmaxf(bS.y - bP.y * bP.y, 0.f) + 1e-5f;
                    const float lncc = 1.0f - cross * rsqrtf(vI * vJ);
                    accL += lncc * mvala;
                    accM += mvala;
                }
                {
                    const v2f bP = K0*(pP0b+h1b) + K1*(pP1b+pP3b) + K2*pP2b;
                    const v2f bS = K0*(pQ0b+h2b) + K1*(pQ1b+pQ3b) + K2*pQ2b;
                    const float bC = K0*(pC0b+hcb) + K1*(pC1b+pC3b) + K2*pC2b;
                    const float cross = bC - bP.x * bP.y;
                    const float vI = fmaxf(bS.x - bP.x * bP.x, 0.f) + 1e-5f;
                    const float vJ = fmaxf(bS.y - bP.y * bP.y, 0.f) + 1e-5f;
                    const float lncc = 1.0f - cross * rsqrtf(vI * vJ);
                    accL += lncc * mvalb;
                    accM += mvalb;
                }
            }

            pP0a=pP1a; pP1a=pP2a; pP2a=pP3a; pP3a=h1a;
            pQ0a=pQ1a; pQ1a=pQ2a; pQ2a=pQ3a; pQ3a=h2a;
            pC0a=pC1a; pC1a=pC2a; pC2a=pC3a; pC3a=hca;
            pP0b=pP1b; pP1b=pP2b; pP2b=pP3b; pP3b=h1b;
            pQ0b=pQ1b; pQ1b=pQ2b; pQ2b=pQ3b; pQ3b=h2b;
            pC0b=pC1b; pC1b=pC2b; pC2b=pC3b; pC3b=hcb;
        }

        // LDS-only barrier (R11: proven equal to __syncthreads, never worse)
        asm volatile("s_waitcnt lgkmcnt(0)\n\ts_barrier" ::: "memory");
    }

    // ---- reduction (10 waves) ----
#pragma unroll
    for (int off = 32; off > 0; off >>= 1) {
        accL += __shfl_down(accL, off, 64);
        accM += __shfl_down(accM, off, 64);
    }
    const int wave = tid >> 6;
    if ((tid & 63) == 0) { redL[wave] = accL; redM[wave] = accM; }
    __syncthreads();
    if (tid == 0) {
        float sL = 0.f, sM = 0.f;
#pragma unroll
        for (int kk = 0; kk < 10; ++kk) { sL += redL[kk]; sM += redM[kk]; }
        atomicAdd(&acc[0], (double)sL);
        atomicAdd(&acc[1], (double)sM);
    }
}

__global__ void lncc_final(const double* __restrict__ acc, float* __restrict__ out)
{
    out[0] = (float)(acc[0] / (acc[1] + 1e-8));
}

extern "C" void kernel_launch(void* const* d_in, const int* in_sizes, int n_in,
                              void* d_out, int out_size, void* d_ws, size_t ws_size,
                              hipStream_t stream)
{
    const float* A = (const float*)d_in[0];
    const float* B = (const float*)d_in[1];
    const float* M = (const float*)d_in[2];
    double* acc = (double*)d_ws;

    hipMemsetAsync(d_ws, 0, 2 * sizeof(double), stream);

    dim3 grid(WW / TW, HH / TH, NB * NCHUNK);   // (7, 6, 32) = 1344 blocks
    dim3 block(640);
    hipLaunchKernelGGL(lncc_main, grid, block, 0, stream, A, B, M, acc);
    hipLaunchKernelGGL(lncc_final, dim3(1), dim3(1), 0, stream, acc, (float*)d_out);
}

// Round 8
// 227.739 us; speedup vs baseline: 1.0438x; 1.0438x over previous
//
#include <hip/hip_runtime.h>

// LNCC, separable 5-tap Gaussian (sigma=1), fused single pass.
// (N=2, C=1, D=160, H=192, W=224) fp32 -> scalar.
// R13: R11 champion base (115-117us; 1344 blocks, 640 thr, 32x16x20 tile,
//      dbuf LDS, packed-fp32 v2f math, lgkm-only barrier) + two changes:
//      (1) mask value prefetched ONE ITER AHEAD (was issued+consumed in the
//          same iteration -> ~300-900cy L3/HBM latency exposed per barrier
//          interval; only global load not software-pipelined);
//      (2) loop peeled: 6-iter warmup / 17-iter branch-free steady /
//          3-iter epilogue, SAME geometry (R10's peel cut VALU ~10% but its
//          840-block grid starved CUs -- not repeated here). Epilogue
//          arranged so no wasted prefetch is issued (FETCH unchanged).
//      R12 lesson: DCHUNK<20 pays 6-iter fill tax; geometry is settled.

#define NB 2
#define DD 160
#define HH 192
#define WW 224
#define SH 224
#define SD (224*192)
#define SN (224*192*160)

#define TW 32
#define TH 16
#define ROWS (TH+4)          // 20
#define DCHUNK 20
#define NCHUNK (DD/DCHUNK)   // 8

#define K0 0.05448868f
#define K1 0.24420134f
#define K2 0.40261995f

#define BAR() asm volatile("s_waitcnt lgkmcnt(0)\n\ts_barrier" ::: "memory")

typedef float v2f __attribute__((ext_vector_type(2)));
typedef float v4f __attribute__((ext_vector_type(4)));

__global__ __launch_bounds__(640) void lncc_main(
    const float* __restrict__ A, const float* __restrict__ B,
    const float* __restrict__ M, double* __restrict__ acc)
{
    __shared__ v2f  sIJ[2][ROWS][36];   // raw (I,J) + W halo, dbuf
    __shared__ v4f  wbA[2][ROWS][32];   // (bI,bJ,bII,bJJ), dbuf
    __shared__ float wbC[2][ROWS][32];  // bIJ, dbuf
    __shared__ float redL[10], redM[10];

    const int wt = blockIdx.x;           // 0..6
    const int ht = blockIdx.y;           // 0..11
    const int zz = blockIdx.z;           // 0..15
    const int n  = zz >> 3;
    const int dc = zz & 7;
    const int w0 = wt * TW, h0 = ht * TH, d0 = dc * DCHUNK;

    const float* __restrict__ Ai = A + (size_t)n * SN;
    const float* __restrict__ Bi = B + (size_t)n * SN;
    const float* __restrict__ Mi = M + (size_t)n * SN;

    const int tid = threadIdx.x;
    const int r   = tid >> 5;            // 0..19
    const int c   = tid & 31;            // 0..31

    const int gh  = h0 + r - 2;
    const bool hv = (unsigned)gh < (unsigned)HH;
    const int ghc = hv ? gh : 0;
    const int hwm = ghc * SH + (w0 + c);          // 32-bit offsets
    const int gwl = w0 + c - 2, gwr = w0 + c + 2;
    const bool lv = hv && (c < 2)   && (gwl >= 0);
    const bool rv = hv && (c >= 30) && (gwr < WW);
    const bool anyh = lv || rv;
    const int hwh = ghc * SH + (lv ? gwl : (rv ? gwr : 0));
    const int mbase = (h0 + r) * SH + (w0 + c);
    const bool orow = (r < TH);          // wave-uniform (waves 8,9 false)

    // D-direction shift-register pipelines (oldest..newest)
    v2f pP0 = 0.f, pP1 = 0.f, pP2 = 0.f, pP3 = 0.f;   // (bI,bJ)
    v2f pQ0 = 0.f, pQ1 = 0.f, pQ2 = 0.f, pQ3 = 0.f;   // (bII,bJJ)
    float pC0 = 0.f, pC1 = 0.f, pC2 = 0.f, pC3 = 0.f; // bIJ
    float accL = 0.f, accM = 0.f;

    // prefetch registers: next raw slice + next mask value
    v2f nM = 0.f, nH = 0.f;
    float mvN = 0.f;

    auto stage = [&](int pw) {
        sIJ[pw][r][c + 2] = nM;
        if (c < 2)        sIJ[pw][r][c]     = nH;
        else if (c >= 30) sIJ[pw][r][c + 4] = nH;
    };
    auto pref = [&](int dd, bool guard) {
        nM = 0.f; nH = 0.f;
        if (guard) {
            const int dof = dd * SD;
            if (hv)   { nM.x = Ai[dof + hwm]; nM.y = Bi[dof + hwm]; }
            if (anyh) { nH.x = Ai[dof + hwh]; nH.y = Bi[dof + hwh]; }
        }
    };
    auto wblur = [&](int px) {
        const v2f v0 = sIJ[px][r][c];
        const v2f v1 = sIJ[px][r][c + 1];
        const v2f v2 = sIJ[px][r][c + 2];
        const v2f v3 = sIJ[px][r][c + 3];
        const v2f v4 = sIJ[px][r][c + 4];
        const v2f b  = K0*(v0+v4) + K1*(v1+v3) + K2*v2;                  // (bI,bJ)
        const v2f bs = K0*(v0*v0+v4*v4) + K1*(v1*v1+v3*v3) + K2*(v2*v2); // (bII,bJJ)
        const float bij = K0*(v0.x*v0.y+v4.x*v4.y) + K1*(v1.x*v1.y+v3.x*v3.y) + K2*(v2.x*v2.y);
        wbA[px][r][c] = (v4f){b.x, b.y, bs.x, bs.y};
        wbC[px][r][c] = bij;
    };
    auto hblur = [&](int pw, float mval, bool doout) {
        const v4f a0 = wbA[pw][r][c];
        const v4f a1 = wbA[pw][r + 1][c];
        const v4f a2 = wbA[pw][r + 2][c];
        const v4f a3 = wbA[pw][r + 3][c];
        const v4f a4 = wbA[pw][r + 4][c];
        const float c0 = wbC[pw][r][c];
        const float c1 = wbC[pw][r + 1][c];
        const float c2 = wbC[pw][r + 2][c];
        const float c3 = wbC[pw][r + 3][c];
        const float c4 = wbC[pw][r + 4][c];
        const v2f h1 = K0*(a0.xy+a4.xy) + K1*(a1.xy+a3.xy) + K2*a2.xy; // (hI,hJ)
        const v2f h2 = K0*(a0.zw+a4.zw) + K1*(a1.zw+a3.zw) + K2*a2.zw; // (hII,hJJ)
        const float hc = K0*(c0+c4) + K1*(c1+c3) + K2*c2;

        if (doout) {
            const v2f bP = K0*(pP0+h1) + K1*(pP1+pP3) + K2*pP2;   // (bI,bJ)
            const v2f bS = K0*(pQ0+h2) + K1*(pQ1+pQ3) + K2*pQ2;   // (bII,bJJ)
            const float bC = K0*(pC0+hc) + K1*(pC1+pC3) + K2*pC2; // bIJ
            const float cross = bC - bP.x * bP.y;
            const float vI = fmaxf(bS.x - bP.x * bP.x, 0.f) + 1e-5f;
            const float vJ = fmaxf(bS.y - bP.y * bP.y, 0.f) + 1e-5f;
            const float lncc = 1.0f - cross * rsqrtf(vI * vJ);
            accL += lncc * mval;
            accM += mval;
        }

        pP0 = pP1; pP1 = pP2; pP2 = pP3; pP3 = h1;
        pQ0 = pQ1; pQ1 = pQ2; pQ2 = pQ3; pQ3 = h2;
        pC0 = pC1; pC1 = pC2; pC2 = pC3; pC3 = hc;
    };

    // ---- initial prefetch: slice d0-2 (negative only for dc==0) ----
    {
        const int dd = d0 - 2;
        pref(dd, dd >= 0);
    }

    // ---- warmup: k = 0..5 (predicated, no outputs) ----
    for (int k = 0; k < 6; ++k) {
        const int pw = k & 1, px = pw ^ 1;
        stage(pw);
        const int dd = d0 - 1 + k;        // d0-1 .. d0+4 (< DD always)
        pref(dd, dd >= 0);
        if (k == 5 && orow) mvN = Mi[d0 * SD + mbase];   // mask for k=6
        if (k >= 1) wblur(px);
        if (k >= 2 && orow) hblur(pw, 0.f, false);
        BAR();
    }

    // ---- steady: k = 6..22 (17 iters, branch-free body) ----
    int moff = (d0 + 1) * SD + mbase;     // mask offset for next iter
#pragma unroll 2
    for (int k = 6; k < 23; ++k) {
        const int pw = k & 1, px = pw ^ 1;
        stage(pw);
        const int dd = d0 - 1 + k;        // d0+5 .. d0+21
        pref(dd, dd < DD);                // uniform guard; only dc==7 tail trips
        const float mval = mvN;
        if (orow) { mvN = Mi[moff]; moff += SD; }
        wblur(px);
        if (orow) hblur(pw, mval, true);
        BAR();
    }

    // ---- epilogue: k = 23, 24, 25 ----
    {   // k = 23: last stage (slice d0+21), no raw prefetch
        stage(1);
        const float mval = mvN;
        if (orow) mvN = Mi[moff];                  // dout = d0+18 (for k=24)
        wblur(0);
        if (orow) hblur(1, mval, true);
        BAR();
    }
    {   // k = 24: last W-blur
        const float mval = mvN;
        if (orow) mvN = Mi[(d0 + 19) * SD + mbase];   // dout = d0+19 (for k=25)
        wblur(1);
        if (orow) hblur(0, mval, true);
        BAR();
    }
    {   // k = 25: last H-blur + output
        if (orow) hblur(1, mvN, true);
    }

    // ---- reduction ----
#pragma unroll
    for (int off = 32; off > 0; off >>= 1) {
        accL += __shfl_down(accL, off, 64);
        accM += __shfl_down(accM, off, 64);
    }
    const int wave = tid >> 6;
    if ((tid & 63) == 0) { redL[wave] = accL; redM[wave] = accM; }
    __syncthreads();
    if (tid == 0) {
        float sL = 0.f, sM = 0.f;
#pragma unroll
        for (int kk = 0; kk < 10; ++kk) { sL += redL[kk]; sM += redM[kk]; }
        atomicAdd(&acc[0], (double)sL);
        atomicAdd(&acc[1], (double)sM);
    }
}

__global__ void lncc_final(const double* __restrict__ acc, float* __restrict__ out)
{
    out[0] = (float)(acc[0] / (acc[1] + 1e-8));
}

extern "C" void kernel_launch(void* const* d_in, const int* in_sizes, int n_in,
                              void* d_out, int out_size, void* d_ws, size_t ws_size,
                              hipStream_t stream)
{
    const float* A = (const float*)d_in[0];
    const float* B = (const float*)d_in[1];
    const float* M = (const float*)d_in[2];
    double* acc = (double*)d_ws;

    hipMemsetAsync(d_ws, 0, 2 * sizeof(double), stream);

    dim3 grid(WW / TW, HH / TH, NB * NCHUNK);   // (7, 12, 16) = 1344 blocks
    dim3 block(640);
    hipLaunchKernelGGL(lncc_main, grid, block, 0, stream, A, B, M, acc);
    hipLaunchKernelGGL(lncc_final, dim3(1), dim3(1), 0, stream, acc, (float*)d_out);
}